// Round 15
// baseline (243.741 us; speedup 1.0000x reference)
//
#include <hip/hip_runtime.h>

// SNN with "swapped outputs" bug: stored state = spike (binary), forwarded
// value = membrane. reset = (spk_prev > 1) == 0 always -> mem = cur + 0.9*spk_prev.
// Constant input -> spike patterns fixate: mem0 const t>=1, mem1 t>=2, out t>=3.
// GEMM0 (256x2048,K=1024); GEMM1 cur1(0) only (M=256,K=2048) + sparse spike
// update cur1(inf) = cur1(0) + 0.9*sum_{k in spikes(b)} W1T[k,:]  (~4% density);
// GEMM2 {mem1(0),mem1(1),mem1(inf)} (M=768,N=1024,K=2048); broadcast t>=3.
// Split-bf16 [h|l]: Ah.Wh + Ah.Wl + Al.Wh as one logical K'=3K GEMM; err ~1e-5.
// f64 fixup of elements within SDELTA=1e-3 of decision points -> exact decisions;
// spike LISTS are exact (certain spikes from epilogue, borderline from fixup).
//
// Round-13 lesson: persistent mega-kernel at 1 blk/CU is latency-starved (3x
// slower); 201us = real work. Round 14: (a) GEMM1 halved via sparse update
// (needs f32 W1T, transposed in cvt), (b) GEMM LDS bank-conflict fix: linear
// gload_lds dest + XOR-pre-swizzled GLOBAL source + XOR on ds_read (rule #21).

typedef unsigned short ushort_t;
typedef __attribute__((ext_vector_type(8))) short bf16x8;
typedef __attribute__((ext_vector_type(4))) float f32x4;

#define SDELTA 1.0e-3f
#define LCAP 65536

__device__ inline ushort_t f2bf(float f) {       // RNE f32 -> bf16
    unsigned u = __float_as_uint(f);
    u += 0x7FFFu + ((u >> 16) & 1u);
    return (ushort_t)(u >> 16);
}
__device__ inline float bf2f(ushort_t h) { return __uint_as_float((unsigned)h << 16); }
__device__ inline float4 ld4(const float* p) { return *reinterpret_cast<const float4*>(p); }

__device__ inline void gload16(const void* g, void* l) {
    __builtin_amdgcn_global_load_lds(
        (__attribute__((address_space(1))) void*)g,
        (__attribute__((address_space(3))) void*)l, 16, 0, 0);
}

// ---- 128x128 split-K GEMM over logical K'=3K, physical [h|l] storage ----
// 1D grid nwg = nx*ny*S (nwg%8==0); XCD-chunked swizzle; Kc segment-aligned.
// LDS: linear dest (gload_lds), XOR-swizzled global source column, XOR reads.
__global__ __launch_bounds__(256) void gemm_splitk(
    const ushort_t* __restrict__ A,   // [M, 2K] bf16: [Ah|Al]
    const ushort_t* __restrict__ W,   // [N, 2K] bf16: [Wh|Wl]
    float* __restrict__ P,            // [S, M, N] f32 partials
    int M, int N, int K, int Kc, int nx, int ny)
{
    __shared__ ushort_t As[128 * 64];
    __shared__ ushort_t Ws[128 * 64];

    const int nwg = gridDim.x;
    const int lin = blockIdx.x;
    const int swzb = (lin & 7) * (nwg >> 3) + (lin >> 3);
    const int nxy = nx * ny;
    const int bz  = swzb / nxy;
    const int rem = swzb - bz * nxy;
    const int by  = rem / nx;
    const int bx  = rem - by * nx;

    const int tid  = threadIdx.x;
    const int lane = tid & 63;
    const int wid  = tid >> 6;
    const int row0 = by * 128;
    const int col0 = bx * 128;
    const int k0   = bz * Kc;          // logical k in [0, 3K)
    const int st   = 2 * K;            // physical row stride
    const int aoff = (k0 < K) ? k0 : (k0 - K);           // A logical [h,h,l]
    const int woff = (k0 < 2 * K) ? k0 : (k0 - 2 * K);   // W logical [h,l,h]

    // staging: lane (r = lane>>3, c = lane&7) loads global chunk c ^ (r&7)
    const int srow = wid * 32 + (lane >> 3);
    const int scol = (((lane & 7) ^ ((lane >> 3) & 7))) * 8;
    const ushort_t* Ag = A + (size_t)(row0 + srow) * st + aoff + scol;
    const ushort_t* Wg = W + (size_t)(col0 + srow) * st + woff + scol;

    const int wr = wid >> 1, wc = wid & 1;
    const int l15 = lane & 15;
    const int kh  = lane >> 4;
    const int swz8 = l15 & 7;
    const int ch0 = ((kh + 0) ^ swz8) * 8;   // ks=0 chunk (elements)
    const int ch1 = ((kh + 4) ^ swz8) * 8;   // ks=1 chunk
    int aRow[4], bRow[4];
#pragma unroll
    for (int m = 0; m < 4; ++m) aRow[m] = (wr * 64 + m * 16 + l15) * 64;
#pragma unroll
    for (int n = 0; n < 4; ++n) bRow[n] = (wc * 64 + n * 16 + l15) * 64;

    f32x4 acc[4][4] = {};
    const int NIT = Kc / 64;

    for (int it = 0; it < NIT; ++it) {
        const int kk = it * 64;
#pragma unroll
        for (int i = 0; i < 4; ++i) {
            gload16(Ag + (size_t)(i * 8) * st + kk, &As[(wid * 32 + i * 8) * 64]);
            gload16(Wg + (size_t)(i * 8) * st + kk, &Ws[(wid * 32 + i * 8) * 64]);
        }
        __syncthreads();
#pragma unroll
        for (int ks = 0; ks < 2; ++ks) {
            const int ch = ks ? ch1 : ch0;
            bf16x8 af[4], bf[4];
#pragma unroll
            for (int m = 0; m < 4; ++m)
                af[m] = *reinterpret_cast<const bf16x8*>(&As[aRow[m] + ch]);
#pragma unroll
            for (int n = 0; n < 4; ++n)
                bf[n] = *reinterpret_cast<const bf16x8*>(&Ws[bRow[n] + ch]);
#pragma unroll
            for (int m = 0; m < 4; ++m)
#pragma unroll
                for (int n = 0; n < 4; ++n)
                    acc[m][n] = __builtin_amdgcn_mfma_f32_16x16x32_bf16(
                        af[m], bf[n], acc[m][n], 0, 0, 0);
        }
        __syncthreads();
    }

    float* Pp = P + ((size_t)bz * M + row0) * N + col0;
#pragma unroll
    for (int n = 0; n < 4; ++n) {
        const int col = wc * 64 + n * 16 + l15;
#pragma unroll
        for (int m = 0; m < 4; ++m) {
            const int rb = wr * 64 + m * 16 + kh * 4;
#pragma unroll
            for (int i = 0; i < 4; ++i)
                Pp[(size_t)(rb + i) * N + col] = acc[m][n][i];
        }
    }
}

// ---------------- split-conversions ([h|l]) + W1 f32 transpose + ctr zero ----------------
__device__ inline void do_split(const float4* src, ushort_t* dst, int i, int logK)
{
    float4 v = src[i];
    const int K = 1 << logK;
    const int e0 = i * 4;
    const int r = e0 >> logK, k = e0 & (K - 1);
    ushort_t* row = dst + (size_t)r * 2 * K;
    ushort4 h, l;
    h.x = f2bf(v.x); l.x = f2bf(v.x - bf2f(h.x));
    h.y = f2bf(v.y); l.y = f2bf(v.y - bf2f(h.y));
    h.z = f2bf(v.z); l.z = f2bf(v.z - bf2f(h.z));
    h.w = f2bf(v.w); l.w = f2bf(v.w - bf2f(h.w));
    *reinterpret_cast<ushort4*>(row + k) = h;
    *reinterpret_cast<ushort4*>(row + K + k) = l;
}

__global__ __launch_bounds__(256) void cvt_all(
    const float4* __restrict__ x,  const float4* __restrict__ W0,
    const float4* __restrict__ W1, const float4* __restrict__ W2,
    ushort_t* __restrict__ xb,  ushort_t* __restrict__ Wb0,
    ushort_t* __restrict__ Wb1, ushort_t* __restrict__ Wb2,
    float* __restrict__ W1T, int* __restrict__ ctrs)
{
    __shared__ float tile[64 * 65];
    const int b = blockIdx.x, tid = threadIdx.x;
    if (b == 0 && tid < 4) ctrs[tid * 16] = 0;
    if (b < 256)        do_split(x,  xb,  b * 256 + tid,          10);
    else if (b < 2304)  do_split(W0, Wb0, (b - 256) * 256 + tid,  10);
    else if (b < 6400)  do_split(W1, Wb1, (b - 2304) * 256 + tid, 11);
    else if (b < 8448)  do_split(W2, Wb2, (b - 6400) * 256 + tid, 11);
    else {
        // 64x64 tiled transpose of W1 (f32) -> W1T;  W1T[n_col][k_row]=W1[k][n]
        const float* W1f = (const float*)W1;
        const int tb = b - 8448;               // 0..1023
        const int tr = tb >> 5, tc = tb & 31;  // 32x32 grid of 64x64 tiles
        const int rr = tid >> 4;               // 0..15
        const int c4 = (tid & 15) * 4;
#pragma unroll
        for (int jj = 0; jj < 4; ++jj) {
            const int r = rr + jj * 16;
            float4 v = *reinterpret_cast<const float4*>(
                W1f + (size_t)(tr * 64 + r) * 2048 + tc * 64 + c4);
            tile[r * 65 + c4 + 0] = v.x;
            tile[r * 65 + c4 + 1] = v.y;
            tile[r * 65 + c4 + 2] = v.z;
            tile[r * 65 + c4 + 3] = v.w;
        }
        __syncthreads();
#pragma unroll
        for (int jj = 0; jj < 4; ++jj) {
            const int r = rr + jj * 16;
            float4 o;
            o.x = tile[(c4 + 0) * 65 + r];
            o.y = tile[(c4 + 1) * 65 + r];
            o.z = tile[(c4 + 2) * 65 + r];
            o.w = tile[(c4 + 3) * 65 + r];
            *reinterpret_cast<float4*>(
                W1T + (size_t)(tc * 64 + r) * 2048 + tr * 64 + c4) = o;
        }
    }
}

// ---------------- wave compaction of flagged indices ----------------
__device__ inline void emit(const int* loc, int lc, int* list, int* counter)
{
    const int lane = threadIdx.x & 63;
    int inc = lc;
#pragma unroll
    for (int off = 1; off < 64; off <<= 1) {
        int t = __shfl_up(inc, off);
        if (lane >= off) inc += t;
    }
    const int total = __shfl(inc, 63);
    int base = 0;
    if (lane == 63 && total) base = atomicAdd(counter, total);
    base = __shfl(base, 63);
    const int excl = inc - lc;
    for (int j = 0; j < lc; ++j) {
        int p = base + excl + j;
        if (p < LCAP) list[p] = loc[j];
    }
}

__device__ inline int flag4(float4 v, int e0, int* loc, int lc)
{
    float vv[4] = {v.x, v.y, v.z, v.w};
#pragma unroll
    for (int c = 0; c < 4; ++c)
        if ((fabsf(vv[c] - 1.0f) < SDELTA) || (fabsf(vv[c] - 0.1f) < SDELTA))
            loc[lc++] = e0 + c;
    return lc;
}

__device__ inline int spike4(float4 v, int e0, int* loc, int lc)   // certain spikes
{
    float vv[4] = {v.x, v.y, v.z, v.w};
#pragma unroll
    for (int c = 0; c < 4; ++c)
        if (vv[c] >= 1.0f + SDELTA) loc[lc++] = e0 + c;
    return lc;
}

__device__ inline void wsplit2(ushort_t* row, int k, float4 v)   // [h|l], width 4096
{
    ushort4 h, l;
    h.x = f2bf(v.x); l.x = f2bf(v.x - bf2f(h.x));
    h.y = f2bf(v.y); l.y = f2bf(v.y - bf2f(h.y));
    h.z = f2bf(v.z); l.z = f2bf(v.z - bf2f(h.z));
    h.w = f2bf(v.w); l.w = f2bf(v.w - bf2f(h.w));
    *reinterpret_cast<ushort4*>(row + k) = h;
    *reinterpret_cast<ushort4*>(row + 2048 + k) = l;
}

__device__ inline void patch2(ushort_t* row, int c, float v)
{
    ushort_t h = f2bf(v);
    ushort_t l = f2bf(v - bf2f(h));
    row[c] = h; row[2048 + c] = l;
}

__device__ inline float4 lifstep(float4 cur, float4 gate)
{
    float4 o;
    o.x = cur.x + ((gate.x > 1.0f) ? 0.9f : 0.0f);
    o.y = cur.y + ((gate.y > 1.0f) ? 0.9f : 0.0f);
    o.z = cur.z + ((gate.z > 1.0f) ? 0.9f : 0.0f);
    o.w = cur.w + ((gate.w > 1.0f) ? 0.9f : 0.0f);
    return o;
}

__device__ inline double wred(double p)
{
#pragma unroll
    for (int off = 32; off; off >>= 1) p += __shfl_down(p, off);
    return __shfl(p, 0);
}

// ---- layer 0 epilogue: reduce S=12 + bias, flag-scan, spike-scan, C0, A1 lo [h|l] ----
__global__ __launch_bounds__(256) void fused0(
    const float4* __restrict__ P, const float* __restrict__ bias,
    float4* __restrict__ C0, ushort_t* __restrict__ A1b,
    int* __restrict__ list, int* __restrict__ counter,
    int* __restrict__ slist, int* __restrict__ scnt)
{
    const int i = blockIdx.x * 256 + threadIdx.x;   // < 131072
    float4 s = P[i];
#pragma unroll
    for (int j = 1; j < 12; ++j) {
        float4 t = P[(size_t)j * 131072 + i];
        s.x += t.x; s.y += t.y; s.z += t.z; s.w += t.w;
    }
    const float4 bv = *reinterpret_cast<const float4*>(bias + ((i * 4) & 2047));
    s.x += bv.x; s.y += bv.y; s.z += bv.z; s.w += bv.w;
    C0[i] = s;
    int loc[4];
    int lc = flag4(s, i * 4, loc, 0);
    emit(loc, lc, list, counter);
    int sl[4];
    int sc = spike4(s, i * 4, sl, 0);
    emit(sl, sc, slist, scnt);
    const int e0 = i * 4, r = e0 >> 11, k = e0 & 2047;
    wsplit2(A1b + (size_t)r * 4096, k, s);     // lo half only (cur1(0) path)
}

// ---- fixup0: exact f64 dot; patch C0 + A1b lo; append exact borderline spikes ----
__global__ __launch_bounds__(256) void fixup0(
    float* __restrict__ C0, ushort_t* __restrict__ A1b,
    const float* __restrict__ X, const float* __restrict__ W0,
    const float* __restrict__ b0,
    const int* __restrict__ list, const int* __restrict__ counter,
    int* __restrict__ slist, int* __restrict__ scnt)
{
    const int lane = threadIdx.x & 63;
    const int wave = (blockIdx.x * 256 + threadIdx.x) >> 6;
    const int nw = gridDim.x * 4;
    const int nbad = min(*counter, LCAP);
    const int chunk = (nbad + nw - 1) / nw;
    for (int e = wave * chunk; e < min(wave * chunk + chunk, nbad); ++e) {
        const int idx = list[e];
        const int rr = idx >> 11, cc = idx & 2047;
        double p = 0.0;
        for (int k = lane * 4; k < 1024; k += 256) {
            float4 a4 = ld4(X + (size_t)rr * 1024 + k);
            float4 w4 = ld4(W0 + (size_t)cc * 1024 + k);
            p = fma((double)a4.x, (double)w4.x, p);
            p = fma((double)a4.y, (double)w4.y, p);
            p = fma((double)a4.z, (double)w4.z, p);
            p = fma((double)a4.w, (double)w4.w, p);
        }
        const double tot = wred(p);
        if (lane == 0) {
            float c = (float)(tot + (double)b0[cc]);
            C0[idx] = c;
            patch2(A1b + (size_t)rr * 4096, cc, c);
            if (c > 1.0f) {                       // exact spike decision
                int ppos = atomicAdd(scnt, 1);
                if (ppos < LCAP) slist[ppos] = idx;
            }
        }
    }
}

// ---- sparse delta: Delta[b,n] = 0.9 * sum_{k in spikes(b)} W1T[k,n]  (f64 acc) ----
__global__ __launch_bounds__(256) void sdelta1(
    const int* __restrict__ slist, const int* __restrict__ scnt,
    const float* __restrict__ W1T, float* __restrict__ Delta)
{
    __shared__ int mk[2048];
    __shared__ int mcnt;
    const int tid = threadIdx.x;
    const int b  = blockIdx.x & 255;
    const int nr = blockIdx.x >> 8;        // 0..3 -> n range of 512
    if (tid == 0) mcnt = 0;
    __syncthreads();
    const int ns = min(*scnt, LCAP);
    for (int t = tid; t < ns; t += 256) {
        const int idx = slist[t];
        if ((idx >> 11) == b) {
            int p = atomicAdd(&mcnt, 1);
            mk[p] = idx & 2047;
        }
    }
    __syncthreads();
    const int n0 = nr * 512 + tid * 2;
    double a0 = 0.0, a1 = 0.0;
    const int m = mcnt;
    for (int j = 0; j < m; ++j) {
        const float* wr = W1T + (size_t)mk[j] * 2048 + n0;
        a0 += (double)wr[0];
        a1 += (double)wr[1];
    }
    Delta[(size_t)b * 2048 + n0]     = (float)(0.9 * a0);
    Delta[(size_t)b * 2048 + n0 + 1] = (float)(0.9 * a1);
}

// ---- layer 1 epilogue: reduce S=12 (M=256), ci = c0 + Delta, scan, C1, A2 [h|l] ----
__global__ __launch_bounds__(256) void fused1(
    const float4* __restrict__ P, const float* __restrict__ bias,
    const float4* __restrict__ Delta,
    float4* __restrict__ C1, ushort_t* __restrict__ A2b,
    int* __restrict__ list, int* __restrict__ counter)
{
    const int i = blockIdx.x * 256 + threadIdx.x;   // < 131072
    float4 c0 = P[i];
#pragma unroll
    for (int j = 1; j < 12; ++j) {
        float4 t = P[(size_t)j * 131072 + i];
        c0.x += t.x; c0.y += t.y; c0.z += t.z; c0.w += t.w;
    }
    const float4 bv = *reinterpret_cast<const float4*>(bias + ((i * 4) & 2047));
    c0.x += bv.x; c0.y += bv.y; c0.z += bv.z; c0.w += bv.w;
    const float4 dv = Delta[i];
    float4 ci;
    ci.x = c0.x + dv.x; ci.y = c0.y + dv.y; ci.z = c0.z + dv.z; ci.w = c0.w + dv.w;
    C1[i] = c0;
    C1[131072 + i] = ci;
    int loc[8];
    int lc = flag4(c0, i * 4, loc, 0);
    lc = flag4(ci, (131072 + i) * 4, loc, lc);
    emit(loc, lc, list, counter);
    float4 m1 = lifstep(ci, c0);
    float4 m2 = lifstep(ci, m1);
    const int e0 = i * 4, r = e0 >> 11, k = e0 & 2047;
    wsplit2(A2b + (size_t)r * 4096, k, c0);
    wsplit2(A2b + (size_t)(256 + r) * 4096, k, m1);
    wsplit2(A2b + (size_t)(512 + r) * 4096, k, m2);
}

// ---- fixup1: exact f64 dots (both halves), patch C1 + A2b ----
__global__ __launch_bounds__(256) void fixup1(
    float* __restrict__ C1, ushort_t* __restrict__ A2b,
    const float* __restrict__ C0, const float* __restrict__ W1,
    const float* __restrict__ b1,
    const int* __restrict__ list, const int* __restrict__ counter)
{
    const int lane = threadIdx.x & 63;
    const int wave = (blockIdx.x * 256 + threadIdx.x) >> 6;
    const int nw = gridDim.x * 4;
    const int nbad = min(*counter, LCAP);
    const int chunk = (nbad + nw - 1) / nw;
    for (int e = wave * chunk; e < min(wave * chunk + chunk, nbad); ++e) {
        const int idx = list[e];
        const int rr = idx >> 11, cc = idx & 2047;
        const int rp = rr & 255;
        double p0 = 0.0, p1 = 0.0;
        for (int k = lane * 4; k < 2048; k += 256) {
            float4 a4 = ld4(C0 + (size_t)rp * 2048 + k);   // mem0(0) row
            float4 w4 = ld4(W1 + (size_t)cc * 2048 + k);
            float4 b4 = lifstep(a4, a4);                    // mem0(inf) row
            p0 = fma((double)a4.x, (double)w4.x, p0);
            p0 = fma((double)a4.y, (double)w4.y, p0);
            p0 = fma((double)a4.z, (double)w4.z, p0);
            p0 = fma((double)a4.w, (double)w4.w, p0);
            p1 = fma((double)b4.x, (double)w4.x, p1);
            p1 = fma((double)b4.y, (double)w4.y, p1);
            p1 = fma((double)b4.z, (double)w4.z, p1);
            p1 = fma((double)b4.w, (double)w4.w, p1);
        }
        const double t0 = wred(p0);
        const double t1 = wred(p1);
        if (lane == 0) {
            float c0 = (float)(t0 + (double)b1[cc]);
            float ci = (float)(t1 + (double)b1[cc]);
            C1[(size_t)rp * 2048 + cc] = c0;
            C1[(size_t)(256 + rp) * 2048 + cc] = ci;
            float m1 = ci + ((c0 > 1.0f) ? 0.9f : 0.0f);
            float m2 = ci + ((m1 > 1.0f) ? 0.9f : 0.0f);
            patch2(A2b + (size_t)rp * 4096, cc, c0);
            patch2(A2b + (size_t)(256 + rp) * 4096, cc, m1);
            patch2(A2b + (size_t)(512 + rp) * 4096, cc, m2);
        }
    }
}

// ---- layer 2 epilogue: reduce S=12 + bias + flag-scan -> C2 ----
__global__ __launch_bounds__(256) void reduce_scan2(
    const float4* __restrict__ P, const float* __restrict__ bias,
    float4* __restrict__ C2, int* __restrict__ list, int* __restrict__ counter)
{
    const int i = blockIdx.x * 256 + threadIdx.x;   // < 196608
    float4 s = P[i];
#pragma unroll
    for (int j = 1; j < 12; ++j) {
        float4 t = P[(size_t)j * 196608 + i];
        s.x += t.x; s.y += t.y; s.z += t.z; s.w += t.w;
    }
    const float4 bv = *reinterpret_cast<const float4*>(bias + ((i * 4) & 1023));
    s.x += bv.x; s.y += bv.y; s.z += bv.z; s.w += bv.w;
    C2[i] = s;
    int loc[4];
    int lc = flag4(s, i * 4, loc, 0);
    emit(loc, lc, list, counter);
}

// ---- fixup2: exact f64 dots for the 3 layer-2 variants ----
__global__ __launch_bounds__(256) void fixup2(
    float* __restrict__ C2, const float* __restrict__ C1,
    const float* __restrict__ W2, const float* __restrict__ b2,
    const int* __restrict__ list, const int* __restrict__ counter)
{
    const int lane = threadIdx.x & 63;
    const int wave = (blockIdx.x * 256 + threadIdx.x) >> 6;
    const int nw = gridDim.x * 4;
    const int nbad = min(*counter, LCAP);
    const int chunk = (nbad + nw - 1) / nw;
    for (int e = wave * chunk; e < min(wave * chunk + chunk, nbad); ++e) {
        const int idx = list[e];
        const int rr = idx >> 10, cc = idx & 1023;
        const int rp = rr & 255;
        double pA = 0.0, pB = 0.0, pC = 0.0;
        for (int k = lane * 4; k < 2048; k += 256) {
            float4 c04 = ld4(C1 + (size_t)rp * 2048 + k);
            float4 ci4 = ld4(C1 + (size_t)(256 + rp) * 2048 + k);
            float4 w4  = ld4(W2 + (size_t)cc * 2048 + k);
            float4 m14 = lifstep(ci4, c04);
            float4 m24 = lifstep(ci4, m14);
            pA = fma((double)c04.x, (double)w4.x, pA);
            pA = fma((double)c04.y, (double)w4.y, pA);
            pA = fma((double)c04.z, (double)w4.z, pA);
            pA = fma((double)c04.w, (double)w4.w, pA);
            pB = fma((double)m14.x, (double)w4.x, pB);
            pB = fma((double)m14.y, (double)w4.y, pB);
            pB = fma((double)m14.z, (double)w4.z, pB);
            pB = fma((double)m14.w, (double)w4.w, pB);
            pC = fma((double)m24.x, (double)w4.x, pC);
            pC = fma((double)m24.y, (double)w4.y, pC);
            pC = fma((double)m24.z, (double)w4.z, pC);
            pC = fma((double)m24.w, (double)w4.w, pC);
        }
        const double tA = wred(pA);
        const double tB = wred(pB);
        const double tC = wred(pC);
        if (lane == 0) {
            C2[(size_t)rp * 1024 + cc]         = (float)(tA + (double)b2[cc]);
            C2[(size_t)(256 + rp) * 1024 + cc] = (float)(tB + (double)b2[cc]);
            C2[(size_t)(512 + rp) * 1024 + cc] = (float)(tC + (double)b2[cc]);
        }
    }
}

// Final layer + broadcast; grid.y covers 4 time-slices each.
__global__ __launch_bounds__(256) void lif2_bcast(const float4* __restrict__ c2,
                                                  float4* __restrict__ out, int n4)
{
    int i = blockIdx.x * 256 + threadIdx.x;
    if (i >= n4) return;
    float4 c0 = c2[i], c1 = c2[n4 + i], ci = c2[2 * n4 + i];
    float4 m0 = c0;
    float4 m1 = lifstep(c1, m0);
    float4 m2 = lifstep(ci, m1);
    float4 m3 = lifstep(ci, m2);
    int t0 = blockIdx.y * 4;
#pragma unroll
    for (int j = 0; j < 4; ++j) {
        int t = t0 + j;
        float4 v = (t == 0) ? m0 : (t == 1) ? m1 : (t == 2) ? m2 : m3;
        out[(size_t)t * n4 + i] = v;
    }
}

extern "C" void kernel_launch(void* const* d_in, const int* in_sizes, int n_in,
                              void* d_out, int out_size, void* d_ws, size_t ws_size,
                              hipStream_t stream)
{
    const float* x  = (const float*)d_in[0];  // [256,1024]
    const float* W0 = (const float*)d_in[1];  // [2048,1024]
    const float* b0 = (const float*)d_in[2];
    const float* W1 = (const float*)d_in[3];  // [2048,2048]
    const float* b1 = (const float*)d_in[4];
    const float* W2 = (const float*)d_in[5];  // [1024,2048]
    const float* b2 = (const float*)d_in[6];
    float* out = (float*)d_out;
    float* ws  = (float*)d_ws;

    // ws (floats): C0 0.5M | C1 1M | C2 0.75M | ctrs | lists 3x64K | slist 64K | Delta 0.5M
    float* C0 = ws;
    float* C1 = ws + 524288;
    float* C2 = ws + 1572864;
    int* ctrs  = (int*)(ws + 2359296);   // [0]=flag0 [16]=flag1 [32]=flag2 [48]=spk0
    int* list0 = (int*)(ws + 2359360);
    int* list1 = (int*)(ws + 2424896);
    int* list2 = (int*)(ws + 2490432);
    int* slist = (int*)(ws + 2555968);
    float* Delta = ws + 2621504;         // [256,2048] f32; end 3145792 (~12.6MB)

    // d_out scratch (ALL overwritten by lif2_bcast at the end), float offsets:
    ushort_t* Wb0 = (ushort_t*)(out);               // [2048,2048] bf16 = 2M floats
    ushort_t* Wb1 = (ushort_t*)(out + 2097152);     // [2048,4096] bf16 = 4M floats
    ushort_t* Wb2 = (ushort_t*)(out + 6291456);     // [1024,4096] bf16 = 2M floats
    ushort_t* xb  = (ushort_t*)(out + 8388608);     // [256,2048]  bf16 = 256K floats
    ushort_t* A1b = (ushort_t*)(out + 8650752);     // [256,4096]  bf16 = 512K floats
    ushort_t* A2b = (ushort_t*)(out + 9175040);     // [768,4096]  bf16 = 1.5M floats
    float* W1T    = out + 10747904;                 // [2048,2048] f32 = 4M floats
    float* Pbuf   = out + 14942208;                 // partials, max 9.44M -> 24.38M < 26.2M

    dim3 blk(256);

    // 1: split-conversions + W1 transpose + counter zeroing
    cvt_all<<<dim3(9472), blk, 0, stream>>>((const float4*)x, (const float4*)W0,
                                            (const float4*)W1, (const float4*)W2,
                                            xb, Wb0, Wb1, Wb2, W1T, ctrs);

    // layer 0: K'=3072, Kc=256, S=12 -> 16x2x12 = 384 blocks
    gemm_splitk<<<dim3(384), blk, 0, stream>>>(xb, Wb0, Pbuf, 256, 2048, 1024, 256, 16, 2);
    fused0<<<dim3(512), blk, 0, stream>>>((const float4*)Pbuf, b0, (float4*)C0,
                                          A1b, list0, ctrs + 0, slist, ctrs + 48);
    fixup0<<<dim3(256), blk, 0, stream>>>(C0, A1b, x, W0, b0, list0, ctrs + 0,
                                          slist, ctrs + 48);
    // sparse spike update for cur1(inf)
    sdelta1<<<dim3(1024), blk, 0, stream>>>(slist, ctrs + 48, W1T, Delta);

    // layer 1: M=256 only. K'=6144, Kc=512, S=12 -> 16x2x12 = 384 blocks
    gemm_splitk<<<dim3(384), blk, 0, stream>>>(A1b, Wb1, Pbuf, 256, 2048, 2048, 512, 16, 2);
    fused1<<<dim3(512), blk, 0, stream>>>((const float4*)Pbuf, b1, (const float4*)Delta,
                                          (float4*)C1, A2b, list1, ctrs + 16);
    fixup1<<<dim3(256), blk, 0, stream>>>(C1, A2b, C0, W1, b1, list1, ctrs + 16);

    // layer 2: K'=6144, Kc=512, S=12 -> 8x6x12 = 576 blocks
    gemm_splitk<<<dim3(576), blk, 0, stream>>>(A2b, Wb2, Pbuf, 768, 1024, 2048, 512, 8, 6);
    reduce_scan2<<<dim3(768), blk, 0, stream>>>((const float4*)Pbuf, b2, (float4*)C2,
                                                list2, ctrs + 32);
    fixup2<<<dim3(256), blk, 0, stream>>>(C2, C1, W2, b2, list2, ctrs + 32);

    // layer-2 LIF chain + output broadcast (overwrites all of d_out)
    lif2_bcast<<<dim3(256, 25), blk, 0, stream>>>((const float4*)C2, (float4*)out, 65536);
}

// Round 16
// 185.077 us; speedup vs baseline: 1.3170x; 1.3170x over previous
//
#include <hip/hip_runtime.h>

// SNN with "swapped outputs" bug: stored state = spike (binary), forwarded
// value = membrane. reset = (spk_prev > 1) == 0 always -> mem = cur + 0.9*spk_prev.
// Constant input -> spike patterns fixate: mem0 const t>=1, mem1 t>=2, out t>=3.
// GEMM0 (256x2048,K=1024); GEMM1 {mem0(0),mem0(inf)} (M=512,K=2048);
// GEMM2 {mem1(0),mem1(1),mem1(inf)} (M=768,N=1024,K=2048); broadcast t>=3.
// Split-bf16 [h|l]: Ah.Wh + Ah.Wl + Al.Wh as one logical K'=3K GEMM; err ~1e-5.
// f64 fixup of elements within SDELTA=1e-3 of decision points -> exact decisions.
//
// Round-15 lesson: sparse spike-rank update gathers ~180MB of W1T rows (~= the
// dense GEMM half it replaced) -> net -42us regression. Round 16 = exact
// round-11 structure (201us baseline) + ONLY the verified GEMM LDS swizzle
// (linear gload_lds dest + XOR-pre-swizzled global source + XOR ds_read).

typedef unsigned short ushort_t;
typedef __attribute__((ext_vector_type(8))) short bf16x8;
typedef __attribute__((ext_vector_type(4))) float f32x4;

#define SDELTA 1.0e-3f
#define LCAP 65536

__device__ inline ushort_t f2bf(float f) {       // RNE f32 -> bf16
    unsigned u = __float_as_uint(f);
    u += 0x7FFFu + ((u >> 16) & 1u);
    return (ushort_t)(u >> 16);
}
__device__ inline float bf2f(ushort_t h) { return __uint_as_float((unsigned)h << 16); }
__device__ inline float4 ld4(const float* p) { return *reinterpret_cast<const float4*>(p); }

__device__ inline void gload16(const void* g, void* l) {
    __builtin_amdgcn_global_load_lds(
        (__attribute__((address_space(1))) void*)g,
        (__attribute__((address_space(3))) void*)l, 16, 0, 0);
}

// ---- 128x128 split-K GEMM over logical K'=3K, physical [h|l] storage ----
// 1D grid nwg = nx*ny*S (nwg%8==0); XCD-chunked swizzle; Kc segment-aligned.
// LDS: linear dest (gload_lds), XOR-swizzled global source column, XOR reads.
__global__ __launch_bounds__(256) void gemm_splitk(
    const ushort_t* __restrict__ A,   // [M, 2K] bf16: [Ah|Al]
    const ushort_t* __restrict__ W,   // [N, 2K] bf16: [Wh|Wl]
    float* __restrict__ P,            // [S, M, N] f32 partials
    int M, int N, int K, int Kc, int nx, int ny)
{
    __shared__ ushort_t As[128 * 64];
    __shared__ ushort_t Ws[128 * 64];

    const int nwg = gridDim.x;
    const int lin = blockIdx.x;
    const int swzb = (lin & 7) * (nwg >> 3) + (lin >> 3);
    const int nxy = nx * ny;
    const int bz  = swzb / nxy;
    const int rem = swzb - bz * nxy;
    const int by  = rem / nx;
    const int bx  = rem - by * nx;

    const int tid  = threadIdx.x;
    const int lane = tid & 63;
    const int wid  = tid >> 6;
    const int row0 = by * 128;
    const int col0 = bx * 128;
    const int k0   = bz * Kc;          // logical k in [0, 3K)
    const int st   = 2 * K;            // physical row stride
    const int aoff = (k0 < K) ? k0 : (k0 - K);           // A logical [h,h,l]
    const int woff = (k0 < 2 * K) ? k0 : (k0 - 2 * K);   // W logical [h,l,h]

    // staging: lane (r = lane>>3, c = lane&7) loads global chunk c ^ (r&7);
    // LDS dest linear -> LDS[row][chunk c] = global[row][chunk c^(row&7)]
    const int srow = wid * 32 + (lane >> 3);
    const int scol = (((lane & 7) ^ ((lane >> 3) & 7))) * 8;
    const ushort_t* Ag = A + (size_t)(row0 + srow) * st + aoff + scol;
    const ushort_t* Wg = W + (size_t)(col0 + srow) * st + woff + scol;

    const int wr = wid >> 1, wc = wid & 1;
    const int l15 = lane & 15;
    const int kh  = lane >> 4;
    const int swz8 = l15 & 7;
    const int ch0 = ((kh + 0) ^ swz8) * 8;   // ks=0: global chunk kh, swizzled
    const int ch1 = ((kh + 4) ^ swz8) * 8;   // ks=1: global chunk kh+4
    int aRow[4], bRow[4];
#pragma unroll
    for (int m = 0; m < 4; ++m) aRow[m] = (wr * 64 + m * 16 + l15) * 64;
#pragma unroll
    for (int n = 0; n < 4; ++n) bRow[n] = (wc * 64 + n * 16 + l15) * 64;

    f32x4 acc[4][4] = {};
    const int NIT = Kc / 64;

    for (int it = 0; it < NIT; ++it) {
        const int kk = it * 64;
#pragma unroll
        for (int i = 0; i < 4; ++i) {
            gload16(Ag + (size_t)(i * 8) * st + kk, &As[(wid * 32 + i * 8) * 64]);
            gload16(Wg + (size_t)(i * 8) * st + kk, &Ws[(wid * 32 + i * 8) * 64]);
        }
        __syncthreads();
#pragma unroll
        for (int ks = 0; ks < 2; ++ks) {
            const int ch = ks ? ch1 : ch0;
            bf16x8 af[4], bf[4];
#pragma unroll
            for (int m = 0; m < 4; ++m)
                af[m] = *reinterpret_cast<const bf16x8*>(&As[aRow[m] + ch]);
#pragma unroll
            for (int n = 0; n < 4; ++n)
                bf[n] = *reinterpret_cast<const bf16x8*>(&Ws[bRow[n] + ch]);
#pragma unroll
            for (int m = 0; m < 4; ++m)
#pragma unroll
                for (int n = 0; n < 4; ++n)
                    acc[m][n] = __builtin_amdgcn_mfma_f32_16x16x32_bf16(
                        af[m], bf[n], acc[m][n], 0, 0, 0);
        }
        __syncthreads();
    }

    float* Pp = P + ((size_t)bz * M + row0) * N + col0;
#pragma unroll
    for (int n = 0; n < 4; ++n) {
        const int col = wc * 64 + n * 16 + l15;
#pragma unroll
        for (int m = 0; m < 4; ++m) {
            const int rb = wr * 64 + m * 16 + kh * 4;
#pragma unroll
            for (int i = 0; i < 4; ++i)
                Pp[(size_t)(rb + i) * N + col] = acc[m][n][i];
        }
    }
}

// ---------------- merged split-conversions ([h|l], width 2K) + ctr zero ----------------
__device__ inline void do_split(const float4* src, ushort_t* dst, int i, int logK)
{
    float4 v = src[i];
    const int K = 1 << logK;
    const int e0 = i * 4;
    const int r = e0 >> logK, k = e0 & (K - 1);
    ushort_t* row = dst + (size_t)r * 2 * K;
    ushort4 h, l;
    h.x = f2bf(v.x); l.x = f2bf(v.x - bf2f(h.x));
    h.y = f2bf(v.y); l.y = f2bf(v.y - bf2f(h.y));
    h.z = f2bf(v.z); l.z = f2bf(v.z - bf2f(h.z));
    h.w = f2bf(v.w); l.w = f2bf(v.w - bf2f(h.w));
    *reinterpret_cast<ushort4*>(row + k) = h;
    *reinterpret_cast<ushort4*>(row + K + k) = l;
}

__global__ __launch_bounds__(256) void cvt_all(
    const float4* __restrict__ x,  const float4* __restrict__ W0,
    const float4* __restrict__ W1, const float4* __restrict__ W2,
    ushort_t* __restrict__ xb,  ushort_t* __restrict__ Wb0,
    ushort_t* __restrict__ Wb1, ushort_t* __restrict__ Wb2,
    int* __restrict__ ctrs)
{
    const int b = blockIdx.x, tid = threadIdx.x;
    if (b == 0 && tid < 3) ctrs[tid * 16] = 0;
    if (b < 256)        do_split(x,  xb,  b * 256 + tid,          10);
    else if (b < 2304)  do_split(W0, Wb0, (b - 256) * 256 + tid,  10);
    else if (b < 6400)  do_split(W1, Wb1, (b - 2304) * 256 + tid, 11);
    else                do_split(W2, Wb2, (b - 6400) * 256 + tid, 11);
}

// ---------------- wave compaction of flagged indices ----------------
__device__ inline void emit(const int* loc, int lc, int* list, int* counter)
{
    const int lane = threadIdx.x & 63;
    int inc = lc;
#pragma unroll
    for (int off = 1; off < 64; off <<= 1) {
        int t = __shfl_up(inc, off);
        if (lane >= off) inc += t;
    }
    const int total = __shfl(inc, 63);
    int base = 0;
    if (lane == 63 && total) base = atomicAdd(counter, total);
    base = __shfl(base, 63);
    const int excl = inc - lc;
    for (int j = 0; j < lc; ++j) {
        int p = base + excl + j;
        if (p < LCAP) list[p] = loc[j];
    }
}

__device__ inline int flag4(float4 v, int e0, int* loc, int lc)
{
    float vv[4] = {v.x, v.y, v.z, v.w};
#pragma unroll
    for (int c = 0; c < 4; ++c)
        if ((fabsf(vv[c] - 1.0f) < SDELTA) || (fabsf(vv[c] - 0.1f) < SDELTA))
            loc[lc++] = e0 + c;
    return lc;
}

__device__ inline void wsplit2(ushort_t* row, int k, float4 v)   // [h|l], width 4096
{
    ushort4 h, l;
    h.x = f2bf(v.x); l.x = f2bf(v.x - bf2f(h.x));
    h.y = f2bf(v.y); l.y = f2bf(v.y - bf2f(h.y));
    h.z = f2bf(v.z); l.z = f2bf(v.z - bf2f(h.z));
    h.w = f2bf(v.w); l.w = f2bf(v.w - bf2f(h.w));
    *reinterpret_cast<ushort4*>(row + k) = h;
    *reinterpret_cast<ushort4*>(row + 2048 + k) = l;
}

__device__ inline void patch2(ushort_t* row, int c, float v)
{
    ushort_t h = f2bf(v);
    ushort_t l = f2bf(v - bf2f(h));
    row[c] = h; row[2048 + c] = l;
}

__device__ inline float4 lifstep(float4 cur, float4 gate)
{
    float4 o;
    o.x = cur.x + ((gate.x > 1.0f) ? 0.9f : 0.0f);
    o.y = cur.y + ((gate.y > 1.0f) ? 0.9f : 0.0f);
    o.z = cur.z + ((gate.z > 1.0f) ? 0.9f : 0.0f);
    o.w = cur.w + ((gate.w > 1.0f) ? 0.9f : 0.0f);
    return o;
}

__device__ inline double wred(double p)
{
#pragma unroll
    for (int off = 32; off; off >>= 1) p += __shfl_down(p, off);
    return __shfl(p, 0);
}

// ---- layer 0 epilogue: reduce S=12 + bias, scan, C0 write, A1 [h|l] ----
__global__ __launch_bounds__(256) void fused0(
    const float4* __restrict__ P, const float* __restrict__ bias,
    float4* __restrict__ C0, ushort_t* __restrict__ A1b,
    int* __restrict__ list, int* __restrict__ counter)
{
    const int i = blockIdx.x * 256 + threadIdx.x;   // < 131072
    float4 s = P[i];
#pragma unroll
    for (int j = 1; j < 12; ++j) {
        float4 t = P[(size_t)j * 131072 + i];
        s.x += t.x; s.y += t.y; s.z += t.z; s.w += t.w;
    }
    const float4 bv = *reinterpret_cast<const float4*>(bias + ((i * 4) & 2047));
    s.x += bv.x; s.y += bv.y; s.z += bv.z; s.w += bv.w;
    C0[i] = s;
    int loc[4];
    int lc = flag4(s, i * 4, loc, 0);
    emit(loc, lc, list, counter);
    float4 mi = lifstep(s, s);
    const int e0 = i * 4, r = e0 >> 11, k = e0 & 2047;
    wsplit2(A1b + (size_t)r * 4096, k, s);
    wsplit2(A1b + (size_t)(256 + r) * 4096, k, mi);
}

// ---- layer 1 epilogue: reduce S=12 both halves, scan, C1, A2 [h|l] ----
__global__ __launch_bounds__(256) void fused1(
    const float4* __restrict__ P, const float* __restrict__ bias,
    float4* __restrict__ C1, ushort_t* __restrict__ A2b,
    int* __restrict__ list, int* __restrict__ counter)
{
    const int i = blockIdx.x * 256 + threadIdx.x;   // < 131072
    float4 c0 = P[i];
    float4 ci = P[131072 + i];
#pragma unroll
    for (int j = 1; j < 12; ++j) {
        float4 t0 = P[(size_t)j * 262144 + i];
        float4 t1 = P[(size_t)j * 262144 + 131072 + i];
        c0.x += t0.x; c0.y += t0.y; c0.z += t0.z; c0.w += t0.w;
        ci.x += t1.x; ci.y += t1.y; ci.z += t1.z; ci.w += t1.w;
    }
    const float4 bv = *reinterpret_cast<const float4*>(bias + ((i * 4) & 2047));
    c0.x += bv.x; c0.y += bv.y; c0.z += bv.z; c0.w += bv.w;
    ci.x += bv.x; ci.y += bv.y; ci.z += bv.z; ci.w += bv.w;
    C1[i] = c0;
    C1[131072 + i] = ci;
    int loc[8];
    int lc = flag4(c0, i * 4, loc, 0);
    lc = flag4(ci, (131072 + i) * 4, loc, lc);
    emit(loc, lc, list, counter);
    float4 m1 = lifstep(ci, c0);
    float4 m2 = lifstep(ci, m1);
    const int e0 = i * 4, r = e0 >> 11, k = e0 & 2047;
    wsplit2(A2b + (size_t)r * 4096, k, c0);
    wsplit2(A2b + (size_t)(256 + r) * 4096, k, m1);
    wsplit2(A2b + (size_t)(512 + r) * 4096, k, m2);
}

// ---- layer 2 epilogue: reduce S=12 + bias + scan -> C2 ----
__global__ __launch_bounds__(256) void reduce_scan2(
    const float4* __restrict__ P, const float* __restrict__ bias,
    float4* __restrict__ C2, int* __restrict__ list, int* __restrict__ counter)
{
    const int i = blockIdx.x * 256 + threadIdx.x;   // < 196608
    float4 s = P[i];
#pragma unroll
    for (int j = 1; j < 12; ++j) {
        float4 t = P[(size_t)j * 196608 + i];
        s.x += t.x; s.y += t.y; s.z += t.z; s.w += t.w;
    }
    const float4 bv = *reinterpret_cast<const float4*>(bias + ((i * 4) & 1023));
    s.x += bv.x; s.y += bv.y; s.z += bv.z; s.w += bv.w;
    C2[i] = s;
    int loc[4];
    int lc = flag4(s, i * 4, loc, 0);
    emit(loc, lc, list, counter);
}

// ---------------- fixups: exact f64 dots, patch C and A [h|l] ----------------
__global__ __launch_bounds__(256) void fixup0(
    float* __restrict__ C0, ushort_t* __restrict__ A1b,
    const float* __restrict__ X, const float* __restrict__ W0,
    const float* __restrict__ b0,
    const int* __restrict__ list, const int* __restrict__ counter)
{
    const int lane = threadIdx.x & 63;
    const int wave = (blockIdx.x * 256 + threadIdx.x) >> 6;
    const int nw = gridDim.x * 4;
    const int nbad = min(*counter, LCAP);
    const int chunk = (nbad + nw - 1) / nw;
    for (int e = wave * chunk; e < min(wave * chunk + chunk, nbad); ++e) {
        const int idx = list[e];
        const int rr = idx >> 11, cc = idx & 2047;
        double p = 0.0;
        for (int k = lane * 4; k < 1024; k += 256) {
            float4 a4 = ld4(X + (size_t)rr * 1024 + k);
            float4 w4 = ld4(W0 + (size_t)cc * 1024 + k);
            p = fma((double)a4.x, (double)w4.x, p);
            p = fma((double)a4.y, (double)w4.y, p);
            p = fma((double)a4.z, (double)w4.z, p);
            p = fma((double)a4.w, (double)w4.w, p);
        }
        const double tot = wred(p);
        if (lane == 0) {
            float c = (float)(tot + (double)b0[cc]);
            C0[idx] = c;
            float mi = c + ((c > 1.0f) ? 0.9f : 0.0f);
            patch2(A1b + (size_t)rr * 4096, cc, c);
            patch2(A1b + (size_t)(256 + rr) * 4096, cc, mi);
        }
    }
}

__global__ __launch_bounds__(256) void fixup1(
    float* __restrict__ C1, ushort_t* __restrict__ A2b,
    const float* __restrict__ C0, const float* __restrict__ W1,
    const float* __restrict__ b1,
    const int* __restrict__ list, const int* __restrict__ counter)
{
    const int lane = threadIdx.x & 63;
    const int wave = (blockIdx.x * 256 + threadIdx.x) >> 6;
    const int nw = gridDim.x * 4;
    const int nbad = min(*counter, LCAP);
    const int chunk = (nbad + nw - 1) / nw;
    for (int e = wave * chunk; e < min(wave * chunk + chunk, nbad); ++e) {
        const int idx = list[e];
        const int rr = idx >> 11, cc = idx & 2047;
        const int rp = rr & 255;
        double p0 = 0.0, p1 = 0.0;
        for (int k = lane * 4; k < 2048; k += 256) {
            float4 a4 = ld4(C0 + (size_t)rp * 2048 + k);   // mem0(0) row
            float4 w4 = ld4(W1 + (size_t)cc * 2048 + k);
            float4 b4 = lifstep(a4, a4);                    // mem0(inf) row
            p0 = fma((double)a4.x, (double)w4.x, p0);
            p0 = fma((double)a4.y, (double)w4.y, p0);
            p0 = fma((double)a4.z, (double)w4.z, p0);
            p0 = fma((double)a4.w, (double)w4.w, p0);
            p1 = fma((double)b4.x, (double)w4.x, p1);
            p1 = fma((double)b4.y, (double)w4.y, p1);
            p1 = fma((double)b4.z, (double)w4.z, p1);
            p1 = fma((double)b4.w, (double)w4.w, p1);
        }
        const double t0 = wred(p0);
        const double t1 = wred(p1);
        if (lane == 0) {
            float c0 = (float)(t0 + (double)b1[cc]);
            float ci = (float)(t1 + (double)b1[cc]);
            C1[(size_t)rp * 2048 + cc] = c0;
            C1[(size_t)(256 + rp) * 2048 + cc] = ci;
            float m1 = ci + ((c0 > 1.0f) ? 0.9f : 0.0f);
            float m2 = ci + ((m1 > 1.0f) ? 0.9f : 0.0f);
            patch2(A2b + (size_t)rp * 4096, cc, c0);
            patch2(A2b + (size_t)(256 + rp) * 4096, cc, m1);
            patch2(A2b + (size_t)(512 + rp) * 4096, cc, m2);
        }
    }
}

__global__ __launch_bounds__(256) void fixup2(
    float* __restrict__ C2, const float* __restrict__ C1,
    const float* __restrict__ W2, const float* __restrict__ b2,
    const int* __restrict__ list, const int* __restrict__ counter)
{
    const int lane = threadIdx.x & 63;
    const int wave = (blockIdx.x * 256 + threadIdx.x) >> 6;
    const int nw = gridDim.x * 4;
    const int nbad = min(*counter, LCAP);
    const int chunk = (nbad + nw - 1) / nw;
    for (int e = wave * chunk; e < min(wave * chunk + chunk, nbad); ++e) {
        const int idx = list[e];
        const int rr = idx >> 10, cc = idx & 1023;
        const int rp = rr & 255;
        double pA = 0.0, pB = 0.0, pC = 0.0;
        for (int k = lane * 4; k < 2048; k += 256) {
            float4 c04 = ld4(C1 + (size_t)rp * 2048 + k);
            float4 ci4 = ld4(C1 + (size_t)(256 + rp) * 2048 + k);
            float4 w4  = ld4(W2 + (size_t)cc * 2048 + k);
            float4 m14 = lifstep(ci4, c04);
            float4 m24 = lifstep(ci4, m14);
            pA = fma((double)c04.x, (double)w4.x, pA);
            pA = fma((double)c04.y, (double)w4.y, pA);
            pA = fma((double)c04.z, (double)w4.z, pA);
            pA = fma((double)c04.w, (double)w4.w, pA);
            pB = fma((double)m14.x, (double)w4.x, pB);
            pB = fma((double)m14.y, (double)w4.y, pB);
            pB = fma((double)m14.z, (double)w4.z, pB);
            pB = fma((double)m14.w, (double)w4.w, pB);
            pC = fma((double)m24.x, (double)w4.x, pC);
            pC = fma((double)m24.y, (double)w4.y, pC);
            pC = fma((double)m24.z, (double)w4.z, pC);
            pC = fma((double)m24.w, (double)w4.w, pC);
        }
        const double tA = wred(pA);
        const double tB = wred(pB);
        const double tC = wred(pC);
        if (lane == 0) {
            C2[(size_t)rp * 1024 + cc]         = (float)(tA + (double)b2[cc]);
            C2[(size_t)(256 + rp) * 1024 + cc] = (float)(tB + (double)b2[cc]);
            C2[(size_t)(512 + rp) * 1024 + cc] = (float)(tC + (double)b2[cc]);
        }
    }
}

// Final layer + broadcast; grid.y covers 4 time-slices each.
__global__ __launch_bounds__(256) void lif2_bcast(const float4* __restrict__ c2,
                                                  float4* __restrict__ out, int n4)
{
    int i = blockIdx.x * 256 + threadIdx.x;
    if (i >= n4) return;
    float4 c0 = c2[i], c1 = c2[n4 + i], ci = c2[2 * n4 + i];
    float4 m0 = c0;
    float4 m1 = lifstep(c1, m0);
    float4 m2 = lifstep(ci, m1);
    float4 m3 = lifstep(ci, m2);
    int t0 = blockIdx.y * 4;
#pragma unroll
    for (int j = 0; j < 4; ++j) {
        int t = t0 + j;
        float4 v = (t == 0) ? m0 : (t == 1) ? m1 : (t == 2) ? m2 : m3;
        out[(size_t)t * n4 + i] = v;
    }
}

extern "C" void kernel_launch(void* const* d_in, const int* in_sizes, int n_in,
                              void* d_out, int out_size, void* d_ws, size_t ws_size,
                              hipStream_t stream)
{
    const float* x  = (const float*)d_in[0];  // [256,1024]
    const float* W0 = (const float*)d_in[1];  // [2048,1024]
    const float* b0 = (const float*)d_in[2];
    const float* W1 = (const float*)d_in[3];  // [2048,2048]
    const float* b1 = (const float*)d_in[4];
    const float* W2 = (const float*)d_in[5];  // [1024,2048]
    const float* b2 = (const float*)d_in[6];
    float* out = (float*)d_out;
    float* ws  = (float*)d_ws;

    // ws (floats): C0 0.5M | C1 1M | C2 0.75M | ctrs | lists 3x64K
    float* C0 = ws;
    float* C1 = ws + 524288;
    float* C2 = ws + 1572864;
    int* ctrs  = (int*)(ws + 2359296);
    int* list0 = (int*)(ws + 2359360);
    int* list1 = (int*)(ws + 2424896);
    int* list2 = (int*)(ws + 2490432);

    // d_out scratch (ALL overwritten by lif2_bcast at the end), float offsets:
    ushort_t* Wb0 = (ushort_t*)(out);               // [2048,2048] bf16 = 2M floats
    ushort_t* Wb1 = (ushort_t*)(out + 2097152);     // [2048,4096] bf16 = 4M floats
    ushort_t* Wb2 = (ushort_t*)(out + 6291456);     // [1024,4096] bf16 = 2M floats
    ushort_t* xb  = (ushort_t*)(out + 8388608);     // [256,2048]  bf16 = 256K floats
    ushort_t* A1b = (ushort_t*)(out + 8650752);     // [512,4096]  bf16 = 1M floats
    ushort_t* A2b = (ushort_t*)(out + 9699328);     // [768,4096]  bf16 = 1.5M floats
    float* Pbuf   = out + 11272192;                 // partials, max 12.6M -> 23.9M < 26.2M

    dim3 blk(256);

    // 1: all split-conversions ([h|l]) + counter zeroing
    cvt_all<<<dim3(8448), blk, 0, stream>>>((const float4*)x, (const float4*)W0,
                                            (const float4*)W1, (const float4*)W2,
                                            xb, Wb0, Wb1, Wb2, ctrs);

    // 2-4: layer 0. K'=3072, Kc=256 (seg-aligned), S=12 -> 16x2x12 = 384 blocks
    gemm_splitk<<<dim3(384), blk, 0, stream>>>(xb, Wb0, Pbuf, 256, 2048, 1024, 256, 16, 2);
    fused0<<<dim3(512), blk, 0, stream>>>((const float4*)Pbuf, b0, (float4*)C0,
                                          A1b, list0, ctrs + 0);
    fixup0<<<dim3(256), blk, 0, stream>>>(C0, A1b, x, W0, b0, list0, ctrs + 0);

    // 5-7: layer 1. K'=6144, Kc=512, S=12 -> 16x4x12 = 768 blocks (3/CU)
    gemm_splitk<<<dim3(768), blk, 0, stream>>>(A1b, Wb1, Pbuf, 512, 2048, 2048, 512, 16, 4);
    fused1<<<dim3(512), blk, 0, stream>>>((const float4*)Pbuf, b1, (float4*)C1,
                                          A2b, list1, ctrs + 16);
    fixup1<<<dim3(256), blk, 0, stream>>>(C1, A2b, C0, W1, b1, list1, ctrs + 16);

    // 8-10: layer 2. K'=6144, Kc=512, S=12 -> 8x6x12 = 576 blocks
    gemm_splitk<<<dim3(576), blk, 0, stream>>>(A2b, Wb2, Pbuf, 768, 1024, 2048, 512, 8, 6);
    reduce_scan2<<<dim3(768), blk, 0, stream>>>((const float4*)Pbuf, b2, (float4*)C2,
                                                list2, ctrs + 32);
    fixup2<<<dim3(256), blk, 0, stream>>>(C2, C1, W2, b2, list2, ctrs + 32);

    // 11: layer-2 LIF chain + output broadcast (overwrites all of d_out)
    lif2_bcast<<<dim3(256, 25), blk, 0, stream>>>((const float4*)C2, (float4*)out, 65536);
}